// Round 10
// baseline (242.943 us; speedup 1.0000x reference)
//
#include <hip/hip_runtime.h>
#include <cmath>

#define DEVI __device__ __forceinline__

DEVI float sigm(float x){ return 1.f/(1.f+expf(-x)); }

typedef __attribute__((ext_vector_type(8))) _Float16 half8;
typedef __attribute__((ext_vector_type(4))) _Float16 half4;
typedef __attribute__((ext_vector_type(4))) float float4v;

// ---------------- utility ----------------

__global__ void k_zero(float* __restrict__ p, int n){
  int i = blockIdx.x*256 + threadIdx.x;
  if (i < n) p[i] = 0.f;
}

// ---------------- GEMM helpers ----------------
#define QA 264
#define QB 520
#define QB3 776

template<typename TB> struct BReg;
template<> struct BReg<_Float16>{
  half8 v;
  DEVI void load(const _Float16* p){ v = *(const half8*)p; }
  DEVI half8 get() const { return v; }
};
template<> struct BReg<float>{
  float4v a, b;
  DEVI void load(const float* p){ a = *(const float4v*)p; b = *(const float4v*)(p+4); }
  DEVI half8 get() const {
    half8 h;
    #pragma unroll
    for (int j = 0; j < 4; j++){ h[j] = (_Float16)a[j]; h[4+j] = (_Float16)b[j]; }
    return h;
  }
};

// depth-2 prefetch NT GEMM (fp16 A; TB = fp16/fp32 B with deferred cvt)
template<typename TB>
__global__ __launch_bounds__(256) void gemm_t(
    const _Float16* __restrict__ A, const TB* __restrict__ Bm, float* __restrict__ C,
    int M, int N, int K,
    const float* __restrict__ bias1, const float* __restrict__ bias2)
{
  __shared__ _Float16 Ah[2][8*QA];
  __shared__ _Float16 Bh[2][8*QB];
  const int tid = threadIdx.x;
  const int m0 = blockIdx.y*32, n0 = blockIdx.x*64;
  const int T = K >> 6;
  const int arow = tid >> 3, aq = tid & 7;
  const int brow = tid >> 3, bq = tid & 7;
  int nB0 = n0 + brow;      if (nB0 >= N) nB0 = N - 1;
  int nB1 = n0 + brow + 32; if (nB1 >= N) nB1 = N - 1;
  const _Float16* Aptr = A + (size_t)(m0 + arow)*K + aq*8;
  const TB* Bp0 = Bm + (size_t)nB0*K + bq*8;
  const TB* Bp1 = Bm + (size_t)nB1*K + bq*8;
  const int wA  = aq*QA + arow*8;
  const int wB0 = bq*QB + brow*8;
  const int wB1 = bq*QB + (brow+32)*8;
  const int wv_ = tid >> 6, lane = tid & 63;
  const int fq = lane >> 4, fr = lane & 15;
  const int m16 = (wv_ & 1)*16, nb = (wv_ >> 1)*32;

  half8 ra0, ra1;
  BReg<TB> rb00, rb10, rb01, rb11;
  ra0 = *(const half8*)(Aptr);
  rb00.load(Bp0); rb10.load(Bp1);
  if (T > 1){
    ra1 = *(const half8*)(Aptr + 64);
    rb01.load(Bp0 + 64); rb11.load(Bp1 + 64);
  }
  *(half8*)&Ah[0][wA]  = ra0;
  *(half8*)&Bh[0][wB0] = rb00.get();
  *(half8*)&Bh[0][wB1] = rb10.get();
  __syncthreads();

  float4v acc0 = {0.f,0.f,0.f,0.f}, acc1 = {0.f,0.f,0.f,0.f};
  for (int t = 0; t < T; t++){
    const int cur = t & 1, nxt = cur ^ 1;
    if (t+2 < T){
      if (cur == 0){
        ra0 = *(const half8*)(Aptr + (t+2)*64);
        rb00.load(Bp0 + (t+2)*64); rb10.load(Bp1 + (t+2)*64);
      } else {
        ra1 = *(const half8*)(Aptr + (t+2)*64);
        rb01.load(Bp0 + (t+2)*64); rb11.load(Bp1 + (t+2)*64);
      }
    }
    #pragma unroll
    for (int s = 0; s < 2; s++){
      int q = s*4 + fq;
      half8 a  = *(half8*)&Ah[cur][q*QA + (m16+fr)*8];
      half8 b0 = *(half8*)&Bh[cur][q*QB + (nb+fr)*8];
      half8 b1 = *(half8*)&Bh[cur][q*QB + (nb+16+fr)*8];
      acc0 = __builtin_amdgcn_mfma_f32_16x16x32_f16(a, b0, acc0, 0, 0, 0);
      acc1 = __builtin_amdgcn_mfma_f32_16x16x32_f16(a, b1, acc1, 0, 0, 0);
    }
    if (t+1 < T){
      if (nxt == 1){
        *(half8*)&Ah[1][wA]  = ra1;
        *(half8*)&Bh[1][wB0] = rb01.get();
        *(half8*)&Bh[1][wB1] = rb11.get();
      } else {
        *(half8*)&Ah[0][wA]  = ra0;
        *(half8*)&Bh[0][wB0] = rb00.get();
        *(half8*)&Bh[0][wB1] = rb10.get();
      }
    }
    __syncthreads();
  }

  const int colA = n0 + nb + fr, colB = colA + 16;
  #pragma unroll
  for (int i = 0; i < 4; i++){
    int m = m0 + m16 + fq*4 + i;
    if (colA < N){
      float v = acc0[i];
      if (bias1) v += bias1[colA];
      if (bias2) v += bias2[colA];
      C[(size_t)m*N + colA] = v;
    }
    if (colB < N){
      float v = acc1[i];
      if (bias1) v += bias1[colB];
      if (bias2) v += bias2[colB];
      C[(size_t)m*N + colB] = v;
    }
  }
}

// -------- mega launch 1: gate-GEMM(x-part only, K=1024) [0,256) | link sums [256,512)
// | alloc [512,1024) | mem-prep [1024,1152). The GEMM does NOT depend on mem-prep
// (cin tail is handled as a rank-1 correction in k_lstm2), so mem-prep rides along.
__global__ __launch_bounds__(256) void k_mega1(
    const float* __restrict__ x, const float* __restrict__ W,
    float* __restrict__ gp,
    const float* __restrict__ usage, float* __restrict__ alloc,
    const float* __restrict__ link, float* __restrict__ rsl, float* __restrict__ cslp,
    const float* __restrict__ mem, float* __restrict__ cm, _Float16* __restrict__ mem_h)
{
  extern __shared__ char smraw[];
  const int blk = blockIdx.x, tid = threadIdx.x;
  const int wv = tid >> 6, lane = tid & 63;

  if (blk < 256){
    // ---- gate GEMM over K=[0,1024): gp = x @ W[:,0:1024]^T (i,g,o gates) ----
    _Float16* AhP = (_Float16*)smraw;                                  // [2][8*QA]
    _Float16* BhP = (_Float16*)(smraw + 2*8*QA*sizeof(_Float16));      // [2][8*QB3]
    const int SA = 8*QA, SB = 8*QB3;
    const int m0 = (blk >> 5)*32, c0 = (blk & 31)*32;
    const int T = 16;                              // K = 1024
    const int arow = tid >> 3, aq = tid & 7;
    const int brow = tid >> 3, bq = tid & 7;
    const float* Ap  = x + (size_t)(m0 + arow)*1024 + aq*8;
    const float* Bpi = W + (size_t)(       c0 + brow)*1536 + bq*8;
    const float* Bpg = W + (size_t)(2048 + c0 + brow)*1536 + bq*8;
    const float* Bpo = W + (size_t)(3072 + c0 + brow)*1536 + bq*8;
    const int wA  = aq*QA + arow*8;
    const int wBi = bq*QB3 + brow*8;
    const int wBg = bq*QB3 + (32+brow)*8;
    const int wBo = bq*QB3 + (64+brow)*8;
    const int fq = lane >> 4, fr = lane & 15;
    const int m16 = (wv & 1)*16, c16 = (wv >> 1)*16;

    BReg<float> ax0, ax1, ri0, rg0, ro0, ri1, rg1, ro1;
    ax0.load(Ap);
    ri0.load(Bpi); rg0.load(Bpg); ro0.load(Bpo);
    ax1.load(Ap + 64);
    ri1.load(Bpi + 64); rg1.load(Bpg + 64); ro1.load(Bpo + 64);
    *(half8*)&AhP[wA]  = ax0.get();
    *(half8*)&BhP[wBi] = ri0.get();
    *(half8*)&BhP[wBg] = rg0.get();
    *(half8*)&BhP[wBo] = ro0.get();
    __syncthreads();

    float4v acci = {0.f,0.f,0.f,0.f}, accg = {0.f,0.f,0.f,0.f}, acco = {0.f,0.f,0.f,0.f};
    for (int t = 0; t < T; t++){
      const int cur = t & 1, nxt = cur ^ 1;
      if (t+2 < T){
        if (cur == 0){
          ax0.load(Ap + (t+2)*64);
          ri0.load(Bpi + (t+2)*64); rg0.load(Bpg + (t+2)*64); ro0.load(Bpo + (t+2)*64);
        } else {
          ax1.load(Ap + (t+2)*64);
          ri1.load(Bpi + (t+2)*64); rg1.load(Bpg + (t+2)*64); ro1.load(Bpo + (t+2)*64);
        }
      }
      #pragma unroll
      for (int s = 0; s < 2; s++){
        int q = s*4 + fq;
        half8 a  = *(half8*)&AhP[cur*SA + q*QA + (m16+fr)*8];
        half8 bi = *(half8*)&BhP[cur*SB + q*QB3 + (c16+fr)*8];
        half8 bg = *(half8*)&BhP[cur*SB + q*QB3 + (32+c16+fr)*8];
        half8 bo = *(half8*)&BhP[cur*SB + q*QB3 + (64+c16+fr)*8];
        acci = __builtin_amdgcn_mfma_f32_16x16x32_f16(a, bi, acci, 0, 0, 0);
        accg = __builtin_amdgcn_mfma_f32_16x16x32_f16(a, bg, accg, 0, 0, 0);
        acco = __builtin_amdgcn_mfma_f32_16x16x32_f16(a, bo, acco, 0, 0, 0);
      }
      if (t+1 < T){
        if (nxt == 1){
          *(half8*)&AhP[SA + wA]  = ax1.get();
          *(half8*)&BhP[SB + wBi] = ri1.get();
          *(half8*)&BhP[SB + wBg] = rg1.get();
          *(half8*)&BhP[SB + wBo] = ro1.get();
        } else {
          *(half8*)&AhP[wA]  = ax0.get();
          *(half8*)&BhP[wBi] = ri0.get();
          *(half8*)&BhP[wBg] = rg0.get();
          *(half8*)&BhP[wBo] = ro0.get();
        }
      }
      __syncthreads();
    }

    const int col = c0 + c16 + fr;
    #pragma unroll
    for (int i = 0; i < 4; i++){
      int m = m0 + m16 + fq*4 + i;
      gp[(size_t)m*1024 + col]          = acci[i];
      gp[262144 + (size_t)m*1024 + col] = accg[i];
      gp[524288 + (size_t)m*1024 + col] = acco[i];
    }
  } else if (blk < 512){
    // ---- link: 8 rows/block, all loads independent, reduces at the end ----
    float (*smem)[132] = (float(*)[132])smraw;
    int pb = blk - 256;
    int r0 = pb*8;
    int c0 = tid*8;
    float4v v0[8], v1[8];
    #pragma unroll
    for (int u = 0; u < 8; u++){
      const float* lp = link + (size_t)(r0+u)*2048 + c0;
      v0[u] = *(const float4v*)lp;
      v1[u] = *(const float4v*)(lp+4);
    }
    float colacc[8];
    #pragma unroll
    for (int j = 0; j < 8; j++) colacc[j] = 0.f;
    float rowpart[8];
    #pragma unroll
    for (int u = 0; u < 8; u++){
      float s = 0.f;
      #pragma unroll
      for (int j = 0; j < 4; j++){
        colacc[j]   += v0[u][j]; colacc[4+j] += v1[u][j];
        s += v0[u][j] + v1[u][j];
      }
      rowpart[u] = s;
    }
    #pragma unroll
    for (int o = 1; o < 64; o <<= 1){
      #pragma unroll
      for (int u = 0; u < 8; u++) rowpart[u] += __shfl_xor(rowpart[u], o);
    }
    if (lane == 0){
      #pragma unroll
      for (int u = 0; u < 8; u++) smem[wv][u] = rowpart[u];
    }
    __syncthreads();
    if (tid < 8) rsl[r0+tid] = smem[0][tid]+smem[1][tid]+smem[2][tid]+smem[3][tid];
    float4v w0, w1;
    #pragma unroll
    for (int j = 0; j < 4; j++){ w0[j] = colacc[j]; w1[j] = colacc[4+j]; }
    *(float4v*)&cslp[(size_t)pb*2048 + c0]     = w0;
    *(float4v*)&cslp[(size_t)pb*2048 + c0 + 4] = w1;
  } else if (blk < 1024){
    // ---- alloc: one n per wave ----
    int n = (blk - 512)*4 + wv;
    float un = usage[n];
    float prod = 1.f;
    #pragma unroll
    for (int i = 0; i < 32; i++){
      int m = lane + i*64;
      float um = usage[m];
      bool before = (um < un) || (um == un && m < n);
      prod *= before ? (1.f - um) : 1.f;
    }
    #pragma unroll
    for (int o = 32; o > 0; o >>= 1) prod *= __shfl_xor(prod, o);
    if (lane == 0) alloc[n] = un * prod;
  } else {
    // ---- mem-prep: 16 rows/block, 4 rows/wave, independent reduce chains ----
    float (*smem)[132] = (float(*)[132])smraw;
    int rbase = (blk - 1024)*16 + wv*4;
    float x0[4], x1[4], ss[4];
    #pragma unroll
    for (int u = 0; u < 4; u++){
      const float* a = mem + (size_t)(rbase+u)*128;
      x0[u] = a[lane]; x1[u] = a[lane+64];
    }
    #pragma unroll
    for (int u = 0; u < 4; u++) ss[u] = x0[u]*x0[u] + x1[u]*x1[u];
    #pragma unroll
    for (int o = 1; o < 64; o <<= 1){
      #pragma unroll
      for (int u = 0; u < 4; u++) ss[u] += __shfl_xor(ss[u], o);
    }
    float c0s = 0.f, c1s = 0.f;
    #pragma unroll
    for (int u = 0; u < 4; u++){
      float invn = 1.f / fmaxf(sqrtf(ss[u]), 1e-12f);
      mem_h[(size_t)(rbase+u)*128 + lane]      = (_Float16)(x0[u]*invn);
      mem_h[(size_t)(rbase+u)*128 + 64 + lane] = (_Float16)(x1[u]*invn);
      c0s += x0[u]; c1s += x1[u];
    }
    smem[wv][lane] = c0s; smem[wv][64+lane] = c1s;
    __syncthreads();
    if (tid < 128) atomicAdd(&cm[tid], smem[0][tid]+smem[1][tid]+smem[2][tid]+smem[3][tid]);
  }
}

// rank-1 tail correction + LSTM activation:
//   corr[gate][c] = sum_j (cm[j&127]/2048) * W[gate_row(c), 1024+j]  + biases
//   h[b,c] = sigm(go)*tanh(sigm(gi)*tanh(gg)),  g* = gp*[b,c] + corr
// 128 blocks x 8 c's.
__global__ __launch_bounds__(256) void k_lstm2(
    const float* __restrict__ gp, const float* __restrict__ W,
    const float* __restrict__ cm,
    const float* __restrict__ b_ih, const float* __restrict__ b_hh,
    _Float16* __restrict__ h)
{
  __shared__ float corrL[3][8];
  __shared__ float cmL[128];
  const int blk = blockIdx.x, tid = threadIdx.x;
  const int wv = tid >> 6, lane = tid & 63;
  const int c0 = blk*8;
  if (tid < 128) cmL[tid] = cm[tid] * (1.f/2048.f);
  __syncthreads();
  // phase 1: 24 (gate,cc) rows, one wave per row
  for (int r = wv; r < 24; r += 4){
    int gate = r >> 3, cc = r & 7;
    int off = (gate == 0) ? 0 : ((gate == 1) ? 2048 : 3072);
    int wrow = off + c0 + cc;
    const float* wp = W + (size_t)wrow*1536 + 1024 + lane*8;
    float4v v0 = *(const float4v*)wp;
    float4v v1 = *(const float4v*)(wp+4);
    float s = 0.f;
    #pragma unroll
    for (int j = 0; j < 4; j++){
      s += v0[j]*cmL[(lane*8+j)   & 127];
      s += v1[j]*cmL[(lane*8+4+j) & 127];
    }
    #pragma unroll
    for (int o = 1; o < 64; o <<= 1) s += __shfl_xor(s, o);
    if (lane == 0) corrL[gate][cc] = s + b_ih[wrow] + b_hh[wrow];
  }
  __syncthreads();
  // phase 2: activation, 8 b's per thread
  const int cc = tid & 7, br = tid >> 3;      // br 0..31
  const float ci = corrL[0][cc], cg = corrL[1][cc], co = corrL[2][cc];
  for (int it = 0; it < 8; it++){
    int b = br*8 + it;
    size_t off = (size_t)b*1024 + c0 + cc;
    float gi = gp[off]          + ci;
    float gg = gp[262144 + off] + cg;
    float go = gp[524288 + off] + co;
    float c = sigm(gi) * tanhf(gg);
    h[off] = (_Float16)(sigm(go) * tanhf(c));
  }
}

DEVI float blockReduce128(float v, float* lds2){
  #pragma unroll
  for (int o = 32; o > 0; o >>= 1) v += __shfl_xor(v, o);
  int w = threadIdx.x >> 6;
  __syncthreads();
  if ((threadIdx.x & 63) == 0) lds2[w] = v;
  __syncthreads();
  return lds2[0] + lds2[1];
}

// parse itf; wv_h has invwv folded, rks_h has invk*str folded
__global__ __launch_bounds__(128) void k_parse(const float* __restrict__ itf,
    _Float16* __restrict__ wv_h, float* __restrict__ ev, float* __restrict__ av,
    float* __restrict__ wg_, float* __restrict__ ag_,
    float* __restrict__ rm0, float* __restrict__ rm1, float* __restrict__ rm2,
    _Float16* __restrict__ rks_h)
{
  __shared__ float red[2];
  int b = blockIdx.x, t = threadIdx.x;
  const float* it = itf + (size_t)b*787;
  float wg = sigm(it[256]);
  float ag = sigm(it[257]);
  if (t == 0){ wg_[b] = wg; ag_[b] = ag; }
  float w = it[t];
  av[b*128 + t] = w * wg;
  ev[b*128 + t] = sigm(it[128 + t]) * wg;
  float ss = blockReduce128(w*w, red);
  float invwv = 1.f / fmaxf(sqrtf(ss), 1e-12f);
  wv_h[b*128 + t] = (_Float16)(w * invwv);
  if (t < 4){
    int rr = t;
    float m0v = it[259 + rr*3 + 0], m1v = it[259 + rr*3 + 1], m2v = it[259 + rr*3 + 2];
    float mx = fmaxf(m0v, fmaxf(m1v, m2v));
    float e0 = expf(m0v - mx), e1 = expf(m1v - mx), e2 = expf(m2v - mx);
    float inv = 1.f / (e0 + e1 + e2);
    rm0[b*4 + rr] = e0*inv; rm1[b*4 + rr] = e1*inv; rm2[b*4 + rr] = e2*inv;
  }
  #pragma unroll
  for (int rr = 0; rr < 4; rr++){
    float kv = it[275 + rr*128 + t];
    float ks = blockReduce128(kv*kv, red);
    float sx = it[271 + rr];
    float str = fmaxf(sx, 0.f) + log1pf(expf(-fabsf(sx)));
    float invk = 1.f / fmaxf(sqrtf(ks), 1e-12f);
    rks_h[((size_t)b*4 + rr)*128 + t] = (_Float16)(kv * invk * str);
  }
}

// ww-scores GEMM: C = exp(wv_h @ mem_h^T) + per-row sums into rsum (pre-zeroed)
__global__ __launch_bounds__(256) void k_gemm_wwExp(
    const _Float16* __restrict__ A, const _Float16* __restrict__ Bm,
    float* __restrict__ C, float* __restrict__ rsum)
{
  __shared__ _Float16 Ah[2][8*QA];
  __shared__ _Float16 Bh[2][8*QB];
  const int tid = threadIdx.x;
  const int m0 = blockIdx.y*32, n0 = blockIdx.x*64;
  const int arow = tid >> 3, aq = tid & 7;
  const int brow = tid >> 3, bq = tid & 7;
  const _Float16* Aptr = A + (size_t)(m0 + arow)*128 + aq*8;
  const _Float16* Bp0 = Bm + (size_t)(n0 + brow)*128 + bq*8;
  const _Float16* Bp1 = Bm + (size_t)(n0 + brow + 32)*128 + bq*8;
  const int wA  = aq*QA + arow*8;
  const int wB0 = bq*QB + brow*8;
  const int wB1 = bq*QB + (brow+32)*8;
  const int wv_ = tid >> 6, lane = tid & 63;
  const int fq = lane >> 4, fr = lane & 15;
  const int m16 = (wv_ & 1)*16, nb = (wv_ >> 1)*32;

  half8 ra  = *(const half8*)(Aptr);
  half8 rb0 = *(const half8*)(Bp0);
  half8 rb1 = *(const half8*)(Bp1);
  *(half8*)&Ah[0][wA]  = ra;
  *(half8*)&Bh[0][wB0] = rb0;
  *(half8*)&Bh[0][wB1] = rb1;
  __syncthreads();

  float4v acc0 = {0.f,0.f,0.f,0.f}, acc1 = {0.f,0.f,0.f,0.f};
  for (int t = 0; t < 2; t++){
    const int cur = t & 1, nxt = cur ^ 1;
    if (t == 0){
      ra  = *(const half8*)(Aptr + 64);
      rb0 = *(const half8*)(Bp0 + 64);
      rb1 = *(const half8*)(Bp1 + 64);
    }
    #pragma unroll
    for (int s = 0; s < 2; s++){
      int q = s*4 + fq;
      half8 a  = *(half8*)&Ah[cur][q*QA + (m16+fr)*8];
      half8 b0 = *(half8*)&Bh[cur][q*QB + (nb+fr)*8];
      half8 b1 = *(half8*)&Bh[cur][q*QB + (nb+16+fr)*8];
      acc0 = __builtin_amdgcn_mfma_f32_16x16x32_f16(a, b0, acc0, 0, 0, 0);
      acc1 = __builtin_amdgcn_mfma_f32_16x16x32_f16(a, b1, acc1, 0, 0, 0);
    }
    if (t == 0){
      *(half8*)&Ah[nxt][wA]  = ra;
      *(half8*)&Bh[nxt][wB0] = rb0;
      *(half8*)&Bh[nxt][wB1] = rb1;
    }
    __syncthreads();
  }

  const int colA = n0 + nb + fr, colB = colA + 16;
  #pragma unroll
  for (int i = 0; i < 4; i++){
    int m = m0 + m16 + fq*4 + i;
    float e0 = expf(acc0[i]);
    float e1 = expf(acc1[i]);
    C[(size_t)m*2048 + colA] = e0;
    C[(size_t)m*2048 + colB] = e1;
    float rs = e0 + e1;
    #pragma unroll
    for (int o = 1; o < 16; o <<= 1) rs += __shfl_xor(rs, o);
    if (fr == 0) atomicAdd(&rsum[m], rs);
  }
}

// fused memory update + softmax-weighting + bw/fw + csl reduction
__global__ __launch_bounds__(256) void k_memupdate_fused(const float* __restrict__ ww,
    const float* __restrict__ ev, const float* __restrict__ av,
    const float* __restrict__ mem,
    const float* __restrict__ wg, const float* __restrict__ ag,
    const float* __restrict__ alloc, const float* __restrict__ rsum,
    const float* __restrict__ rsl, const float* __restrict__ cslp,
    _Float16* __restrict__ memn_h, _Float16* __restrict__ memnT_h,
    float* __restrict__ bwm, float* __restrict__ fwm)
{
  __shared__ float Ws[16][34];
  __shared__ float Es[16][132], Vs[16][132];
  __shared__ float lb[128], lf[128];
  __shared__ _Float16 Traw[32][132];
  __shared__ float tbs[256], c1s[256], c2s[256];
  __shared__ float allocL[32];
  __shared__ float sq[8][32], sd[8][32];
  __shared__ float cpart[8][32];
  __shared__ float bwL[32], fwL[32];
  __shared__ float sred[4];
  const int n0 = blockIdx.x*32;
  const int tid = threadIdx.x, tx = tid & 31, ty = tid >> 5;

  {
    float sa = 0.f;
    #pragma unroll
    for (int i = 0; i < 8; i++) sa += alloc[tid + i*256];
    #pragma unroll
    for (int o = 32; o > 0; o >>= 1) sa += __shfl_xor(sa, o);
    if ((tid & 63) == 0) sred[tid >> 6] = sa;
    if (tid < 128){ lb[tid] = 0.f; lf[tid] = 0.f; }
    if (tid < 32) allocL[tid] = alloc[n0 + tid];
    __syncthreads();
    sa = (sred[0]+sred[1]) + (sred[2]+sred[3]);
    float w = wg[tid], a = ag[tid];
    tbs[tid] = w*(0.5f + 0.5f*a*sa);
    c1s[tid] = 0.5f*w / rsum[tid];
    c2s[tid] = 0.5f*w*a;
  }
  {
    int col = n0 + tx;
    float s = 0.f;
    for (int p = ty*32; p < ty*32 + 32; p += 4){
      s += cslp[(size_t)(p+0)*2048 + col] + cslp[(size_t)(p+1)*2048 + col]
         + cslp[(size_t)(p+2)*2048 + col] + cslp[(size_t)(p+3)*2048 + col];
    }
    cpart[ty][tx] = s;
  }
  __syncthreads();

  const int wk = tid >> 4, wn = (tid & 15)*2;
  const int ek = tid >> 4, ec = (tid & 15)*8;
  float ae[4][4] = {}, aa[4][4] = {};
  float qp = 0.f, ddp = 0.f;
  for (int k0 = 0; k0 < 256; k0 += 16){
    float2 vw  = *(const float2*)(ww + (size_t)(k0+wk)*2048 + n0 + wn);
    float4 ve0 = *(const float4*)(ev + (size_t)(k0+ek)*128 + ec);
    float4 ve1 = *(const float4*)(ev + (size_t)(k0+ek)*128 + ec + 4);
    float4 va0 = *(const float4*)(av + (size_t)(k0+ek)*128 + ec);
    float4 va1 = *(const float4*)(av + (size_t)(k0+ek)*128 + ec + 4);
    __syncthreads();
    {
      float cb1 = c1s[k0+wk], cb2 = c2s[k0+wk];
      Ws[wk][wn]   = cb1*vw.x + cb2*allocL[wn];
      Ws[wk][wn+1] = cb1*vw.y + cb2*allocL[wn+1];
    }
    *(float4*)&Es[ek][ec] = ve0; *(float4*)&Es[ek][ec+4] = ve1;
    *(float4*)&Vs[ek][ec] = va0; *(float4*)&Vs[ek][ec+4] = va1;
    __syncthreads();
    #pragma unroll
    for (int k = 0; k < 16; k++){
      float a[4], e[4], v[4];
      #pragma unroll
      for (int i = 0; i < 4; i++) a[i] = Ws[k][ty*4+i];
      #pragma unroll
      for (int j = 0; j < 4; j++){ e[j] = Es[k][tx*4+j]; v[j] = Vs[k][tx*4+j]; }
      #pragma unroll
      for (int i = 0; i < 4; i++)
        #pragma unroll
        for (int j = 0; j < 4; j++){
          ae[i][j] = fmaf(a[i], e[j], ae[i][j]);
          aa[i][j] = fmaf(a[i], v[j], aa[i][j]);
        }
    }
    {
      float w0 = Ws[ty*2+0][tx], w1 = Ws[ty*2+1][tx];
      qp  = fmaf(tbs[k0+ty*2+0], w0, qp);  ddp = fmaf(w0, w0, ddp);
      qp  = fmaf(tbs[k0+ty*2+1], w1, qp);  ddp = fmaf(w1, w1, ddp);
    }
  }
  sq[ty][tx] = qp; sd[ty][tx] = ddp;
  __syncthreads();
  if (tid < 32){
    float q = 0.f, dd = 0.f, cs = 0.f;
    #pragma unroll
    for (int z = 0; z < 8; z++){ q += sq[z][tid]; dd += sd[z][tid]; cs += cpart[z][tid]; }
    float lus = (q - dd) * (1.f/256.f);
    bwL[tid] = (0.9f*cs + 0.1f*lus) * (1.f/2048.f);
    fwL[tid] = (0.9f*rsl[n0+tid] + 0.1f*lus) * (1.f/2048.f);
  }
  __syncthreads();

  float ab[4] = {0,0,0,0}, af[4] = {0,0,0,0};
  #pragma unroll
  for (int i = 0; i < 4; i++){
    int n = n0 + ty*4 + i;
    float bwn = bwL[ty*4+i], fwn = fwL[ty*4+i];
    float v[4]; float ss = 0.f;
    #pragma unroll
    for (int j = 0; j < 4; j++){
      int d = tx*4 + j;
      float em = ae[i][j]*(1.f/256.f), am = aa[i][j]*(1.f/256.f);
      float mv = mem[(size_t)n*128 + d]*(1.f - em) + am;
      v[j] = mv; ss += mv*mv;
      ab[j] = fmaf(bwn, mv, ab[j]);
      af[j] = fmaf(fwn, mv, af[j]);
    }
    #pragma unroll
    for (int o = 1; o < 32; o <<= 1) ss += __shfl_xor(ss, o);
    float invn = 1.f / fmaxf(sqrtf(ss), 1e-12f);
    half4 hn, hr;
    #pragma unroll
    for (int j = 0; j < 4; j++){ hn[j] = (_Float16)(v[j]*invn); hr[j] = (_Float16)v[j]; }
    *(half4*)(memn_h + (size_t)n*128 + tx*4) = hn;
    *(half4*)&Traw[ty*4+i][tx*4] = hr;
  }
  __syncthreads();
  {
    int d = tid >> 1, seg = (tid & 1)*16;
    half8 o0, o1;
    #pragma unroll
    for (int j = 0; j < 8; j++){ o0[j] = Traw[seg+j][d]; o1[j] = Traw[seg+8+j][d]; }
    *(half8*)(memnT_h + (size_t)d*2048 + n0 + seg)     = o0;
    *(half8*)(memnT_h + (size_t)d*2048 + n0 + seg + 8) = o1;
  }
  #pragma unroll
  for (int j = 0; j < 4; j++){
    atomicAdd(&lb[tx*4+j], ab[j]);
    atomicAdd(&lf[tx*4+j], af[j]);
  }
  __syncthreads();
  if (tid < 128){
    atomicAdd(&bwm[tid], lb[tid]);
    atomicAdd(&fwm[tid], lf[tid]);
  }
}

// flash-style fused read addressing — 8 key-chunks of 256 keys (2 s-steps/block)
__global__ __launch_bounds__(256) void k_flash(
    const _Float16* __restrict__ Q, const _Float16* __restrict__ Kh,
    const _Float16* __restrict__ Vt,
    float* __restrict__ pacc, float* __restrict__ pm, float* __restrict__ pl)
{
  __shared__ _Float16 Pl[4][16][32];
  __shared__ float cmb[4][2080];
  __shared__ float scl[4][16];
  const int tid = threadIdx.x;
  const int qt = blockIdx.x >> 3, kc = blockIdx.x & 7;
  const int wv = tid >> 6, lane = tid & 63;
  const int fq = lane >> 4, fr = lane & 15;
  const int kw0 = kc*256 + wv*64;

  half8 aq[4];
  #pragma unroll
  for (int c = 0; c < 4; c++)
    aq[c] = *(const half8*)(Q + (size_t)(qt*16 + fr)*128 + c*32 + fq*8);

  float m[4] = {-3.0e38f,-3.0e38f,-3.0e38f,-3.0e38f};
  float l[4] = {0.f,0.f,0.f,0.f};
  float4v acc[8] = {};
  for (int s = 0; s < 2; s++){
    const int kb = kw0 + s*32;
    float4v S0 = {0,0,0,0}, S1 = {0,0,0,0};
    #pragma unroll
    for (int c = 0; c < 4; c++){
      half8 b0 = *(const half8*)(Kh + (size_t)(kb + fr)*128      + c*32 + fq*8);
      half8 b1 = *(const half8*)(Kh + (size_t)(kb + 16 + fr)*128 + c*32 + fq*8);
      S0 = __builtin_amdgcn_mfma_f32_16x16x32_f16(aq[c], b0, S0, 0, 0, 0);
      S1 = __builtin_amdgcn_mfma_f32_16x16x32_f16(aq[c], b1, S1, 0, 0, 0);
    }
    float mt[4], ps[4];
    #pragma unroll
    for (int i = 0; i < 4; i++) mt[i] = fmaxf(S0[i], S1[i]);
    #pragma unroll
    for (int o = 1; o < 16; o <<= 1){
      #pragma unroll
      for (int i = 0; i < 4; i++) mt[i] = fmaxf(mt[i], __shfl_xor(mt[i], o));
    }
    #pragma unroll
    for (int i = 0; i < 4; i++){
      float mn = fmaxf(m[i], mt[i]);
      float al = expf(m[i] - mn);
      float p0 = expf(S0[i] - mn), p1 = expf(S1[i] - mn);
      S0[i] = p0; S1[i] = p1;
      ps[i] = p0 + p1;
      l[i] *= al;
      m[i] = mn;
      #pragma unroll
      for (int c = 0; c < 8; c++) acc[c][i] *= al;
    }
    #pragma unroll
    for (int o = 1; o < 16; o <<= 1){
      #pragma unroll
      for (int i = 0; i < 4; i++) ps[i] += __shfl_xor(ps[i], o);
    }
    #pragma unroll
    for (int i = 0; i < 4; i++) l[i] += ps[i];
    #pragma unroll
    for (int i = 0; i < 4; i++){
      Pl[wv][fq*4+i][fr]      = (_Float16)S0[i];
      Pl[wv][fq*4+i][16 + fr] = (_Float16)S1[i];
    }
    half8 pf = *(half8*)&Pl[wv][fr][fq*8];
    #pragma unroll
    for (int c = 0; c < 8; c++){
      half8 bv = *(const half8*)(Vt + (size_t)(c*16 + fr)*2048 + kb + fq*8);
      acc[c] = __builtin_amdgcn_mfma_f32_16x16x32_f16(pf, bv, acc[c], 0, 0, 0);
    }
  }
  if (fr == 0){
    #pragma unroll
    for (int i = 0; i < 4; i++){
      cmb[wv][fq*4+i]      = m[i];
      cmb[wv][16 + fq*4+i] = l[i];
    }
  }
  #pragma unroll
  for (int c = 0; c < 8; c++)
    #pragma unroll
    for (int i = 0; i < 4; i++)
      cmb[wv][32 + (fq*4+i)*128 + c*16 + fr] = acc[c][i];
  __syncthreads();
  if (tid < 16){
    float mm = fmaxf(fmaxf(cmb[0][tid], cmb[1][tid]), fmaxf(cmb[2][tid], cmb[3][tid]));
    float ll = 0.f;
    #pragma unroll
    for (int w = 0; w < 4; w++){
      float e = expf(cmb[w][tid] - mm);
      scl[w][tid] = e;
      ll += e * cmb[w][16 + tid];
    }
    pm[blockIdx.x*16 + tid] = mm;
    pl[blockIdx.x*16 + tid] = ll;
  }
  __syncthreads();
  for (int e = tid; e < 2048; e += 256){
    int q = e >> 7;
    float a = scl[0][q]*cmb[0][32+e] + scl[1][q]*cmb[1][32+e]
            + scl[2][q]*cmb[2][32+e] + scl[3][q]*cmb[3][32+e];
    pacc[(size_t)blockIdx.x*2048 + e] = a;
  }
}

// output GEMM with in-kernel read-out combine: prologue builds the 32x512 ro slice
// (8-chunk flash combine + read-mode mix) into LDS; A = concat(h_h, roL).
__global__ __launch_bounds__(256) void gemm_hro(
    const _Float16* __restrict__ Ah_, const float* __restrict__ Bm, float* __restrict__ C,
    const float* __restrict__ bias1,
    const float* __restrict__ pacc, const float* __restrict__ pm, const float* __restrict__ pl,
    const float* __restrict__ rm0, const float* __restrict__ rm1, const float* __restrict__ rm2,
    const float* __restrict__ bwm, const float* __restrict__ fwm)
{
  __shared__ _Float16 Ah[2][8*QA];
  __shared__ _Float16 Bh[2][8*QB];
  __shared__ _Float16 roL[32][512];
  const int tid = threadIdx.x;
  const int m0 = blockIdx.y*32, n0 = blockIdx.x*64;
  const int T = 24;

  // ---- prologue: ro rows m0..m0+31 into LDS ----
  {
    int pr = tid >> 1;                 // 0..127
    int r = pr >> 2, rh = pr & 3;
    int half = tid & 1;
    int row4 = (m0 + r)*4 + rh;
    int qt = row4 >> 4, q = row4 & 15;
    float mm = -3.0e38f;
    #pragma unroll
    for (int kc = 0; kc < 8; kc++) mm = fmaxf(mm, pm[(qt*8+kc)*16 + q]);
    float e[8]; float den = 0.f;
    #pragma unroll
    for (int kc = 0; kc < 8; kc++){
      e[kc] = expf(pm[(qt*8+kc)*16 + q] - mm);
      den += e[kc] * pl[(qt*8+kc)*16 + q];
    }
    float r0v = rm0[row4], r1v = rm1[row4], r2v = rm2[row4];
    float invden = 1.f / den;
    int d0 = half*64;
    for (int dd = 0; dd < 64; dd += 4){
      int d = d0 + dd;
      float4v num = {0.f,0.f,0.f,0.f};
      #pragma unroll
      for (int kc = 0; kc < 8; kc++){
        float4v pv = *(const float4v*)(pacc + (size_t)(qt*8+kc)*2048 + q*128 + d);
        #pragma unroll
        for (int j = 0; j < 4; j++) num[j] += e[kc]*pv[j];
      }
      #pragma unroll
      for (int j = 0; j < 4; j++){
        float pvv = num[j]*invden;
        roL[r][rh*128 + d + j] = (_Float16)(r0v*pvv + r1v*bwm[d+j] + r2v*fwm[d+j]);
      }
    }
  }
  __syncthreads();

  const int arow = tid >> 3, aq = tid & 7;
  const int brow = tid >> 3, bq = tid & 7;
  const int arw = m0 + arow;
  const float* Bp0 = Bm + (size_t)(n0 + brow)*1536 + bq*8;
  const float* Bp1 = Bm + (size_t)(n0 + brow + 32)*1536 + bq*8;
  const int wA  = aq*QA + arow*8;
  const int wB0 = bq*QB + brow*8;
  const int wB1 = bq*QB + (brow+32)*8;
  const int wv_ = tid >> 6, lane = tid & 63;
  const int fq = lane >> 4, fr = lane & 15;
  const int m16 = (wv_ & 1)*16, nb = (wv_ >> 1)*32;

  auto ldA = [&](int k) -> half8 {
    if (k < 1024) return *(const half8*)(Ah_ + (size_t)arw*1024 + k);
    return *(const half8*)&roL[arow][k - 1024];
  };

  half8 ra0, ra1;
  BReg<float> rb00, rb10, rb01, rb11;
  ra0 = ldA(aq*8);
  rb00.load(Bp0); rb10.load(Bp1);
  ra1 = ldA(aq*8 + 64);
  rb01.load(Bp0 + 64); rb11.load(Bp1 + 64);
  *(half8*)&Ah[0][wA]  = ra0;
  *(half8*)&Bh[0][wB0] = rb00.get();
  *(half8*)&Bh[0][wB1] = rb10.get();
  __syncthreads();

  float4v acc0 = {0.f,0.f,0.f,0.f}, acc1 = {0.f,0.f,0.f,0.f};
  for (int t = 0; t < T; t++){
    const int cur = t & 1, nxt = cur ^ 1;
    if (t+2 < T){
      if (cur == 0){
        ra0 = ldA(aq*8 + (t+2)*64);
        rb00.load(Bp0 + (t+2)*64); rb10.load(Bp1 + (t+2)*64);
      } else {
        ra1 = ldA(aq*8 + (t+2)*64);
        rb01.load(Bp0 + (t+2)*64); rb11.load(Bp1 + (t+2)*64);
      }
    }
    #pragma unroll
    for (int s = 0; s < 2; s++){
      int q = s*4 + fq;
      half8 a  = *(half8*)&Ah[cur][q*QA + (m16+fr)*8];
      half8 b0 = *(half8*)&Bh[cur][q*QB + (nb+fr)*8];
      half8 b1 = *(half8*)&Bh[cur][q*QB + (nb+16+fr)*8];
      acc0 = __builtin_amdgcn_mfma_f32_16x16x32_f16(a, b0, acc0, 0, 0, 0);
      acc1 = __builtin_amdgcn_mfma_f32_16x16x32_f16(a, b1, acc1, 0, 0, 0);
    }
    if (t+1 < T){
      if (nxt == 1){
        *(half8*)&Ah[1][wA]  = ra1;
        *(half8*)&Bh[1][wB0] = rb01.get();
        *(half8*)&Bh[1][wB1] = rb11.get();
      } else {
        *(half8*)&Ah[0][wA]  = ra0;
        *(half8*)&Bh[0][wB0] = rb00.get();
        *(half8*)&Bh[0][wB1] = rb10.get();
      }
    }
    __syncthreads();
  }

  const int colA = n0 + nb + fr, colB = colA + 16;
  #pragma unroll
  for (int i = 0; i < 4; i++){
    int m = m0 + m16 + fq*4 + i;
    C[(size_t)m*1024 + colA] = acc0[i] + bias1[colA];
    C[(size_t)m*1024 + colB] = acc1[i] + bias1[colB];
  }
}

// ---------------- launcher ----------------

extern "C" void kernel_launch(void* const* d_in, const int* in_sizes, int n_in,
                              void* d_out, int out_size, void* d_ws, size_t ws_size,
                              hipStream_t stream)
{
  const float* x     = (const float*)d_in[0];
  const float* mem   = (const float*)d_in[1];
  const float* usage = (const float*)d_in[2];
  const float* link  = (const float*)d_in[3];
  const float* W_ih  = (const float*)d_in[4];
  // d_in[5] = W_hh: unused (h0 = 0)
  const float* b_ih  = (const float*)d_in[6];
  const float* b_hh  = (const float*)d_in[7];
  const float* W_if  = (const float*)d_in[8];
  const float* b_if  = (const float*)d_in[9];
  const float* W_out = (const float*)d_in[10];
  const float* b_out = (const float*)d_in[11];
  float* out = (float*)d_out;
  float* ws  = (float*)d_ws;

  // fp32 scratch
  float* cm     = ws + 0;         // 128   (zero region: [0,2688) covers cm,bwm,fwm,rsum)
  float* bwm    = ws + 2176;      // 128
  float* fwm    = ws + 2304;      // 128
  float* rsum   = ws + 2432;      // 256 (exp row sums)
  float* wg     = ws + 6784;      // 256
  float* ag     = ws + 7040;      // 256
  float* rm0    = ws + 7296;      // 1024
  float* rm1    = ws + 8320;      // 1024
  float* rm2    = ws + 9344;      // 1024
  float* alloc  = ws + 10368;     // 2048
  float* rsl    = ws + 12416;     // 2048
  float* ev     = ws + 14464;     // 32768 (B x 128)
  float* av     = ws + 47232;     // 32768
  float* itf    = ws + 1128576;   // 201472 (B x 787)
  float* ww     = ws + 1330048;   // 524288 (B x 2048, exp scores)
  float* pacc   = ws + 1854336;   // 1048576 (512 blocks x 2048)
  float* pm     = ws + 2902912;   // 8192
  float* pl     = ws + 2911104;   // 8192
  // fp16 scratch
  _Float16* wv_h    = (_Float16*)(ws + 2919296);  //  32,768 h
  _Float16* mem_h   = (_Float16*)(ws + 2935680);  // 262,144 h (row-normalized)
  _Float16* memn_h  = (_Float16*)(ws + 3066752);  // 262,144 h (row-normalized)
  _Float16* memnT_h = (_Float16*)(ws + 3197824);  // 262,144 h (transposed raw)
  _Float16* rks_h   = (_Float16*)(ws + 3328896);  // 131,072 h
  _Float16* h_h     = (_Float16*)(ws + 3459968);  // 262,144 h
  float* cslp       = ws + 3591040;               // 524,288 (256 x 2048 col partials)
  float* gp         = ws + 4115328;               // 786,432 (3 planes of B x 1024 gates)
  // total ~4.9M floats = 19.6 MB

  const int SH_MEGA = (2*8*QA + 2*8*QB3) * (int)sizeof(_Float16);   // 33280 B

  // stage 0: zero atomic accumulators (cm, bwm, fwm, rsum)
  k_zero<<<11, 256, 0, stream>>>(ws, 2688);

  // stage 1 (mega): gate GEMM x-part | link row/col sums | alloc | mem-prep
  k_mega1<<<1152, 256, SH_MEGA, stream>>>(x, W_ih, gp, usage, alloc, link, rsl, cslp,
                                          mem, cm, mem_h);

  // stage 2: rank-1 tail correction + LSTM activation -> h_h
  k_lstm2<<<128, 256, 0, stream>>>(gp, W_ih, cm, b_ih, b_hh, h_h);

  // stage 3: interface (B = W_if fp32, deferred-cvt, depth-2 prefetch)
  gemm_t<float><<<dim3(13,8), 256, 0, stream>>>(h_h, W_if, itf, 256, 787, 1024, b_if, nullptr);
  k_parse<<<256, 128, 0, stream>>>(itf, wv_h, ev, av, wg, ag, rm0, rm1, rm2, rks_h);

  // stage 4: write scores -> exp + row sums
  k_gemm_wwExp<<<dim3(32,8), 256, 0, stream>>>(wv_h, mem_h, ww, rsum);

  // stage 5+6: memory update (softmax-weighting on the fly, bwfw + csl fused)
  k_memupdate_fused<<<64, 256, 0, stream>>>(ww, ev, av, mem, wg, ag, alloc, rsum,
                                            rsl, cslp, memn_h, memnT_h, bwm, fwm);

  // stage 7: flash-fused read addressing (8 key-chunks)
  k_flash<<<512, 256, 0, stream>>>(rks_h, memn_h, memnT_h, pacc, pm, pl);

  // stage 8: output projection with in-kernel read-out combine
  gemm_hro<<<dim3(16,8), 256, 0, stream>>>(h_h, W_out, out, b_out,
                                           pacc, pm, pl, rm0, rm1, rm2, bwm, fwm);

  (void)in_sizes; (void)n_in; (void)out_size; (void)ws_size;
}

// Round 11
// 224.864 us; speedup vs baseline: 1.0804x; 1.0804x over previous
//
#include <hip/hip_runtime.h>
#include <cmath>

#define DEVI __device__ __forceinline__

DEVI float sigm(float x){ return 1.f/(1.f+expf(-x)); }

typedef __attribute__((ext_vector_type(8))) _Float16 half8;
typedef __attribute__((ext_vector_type(4))) _Float16 half4;
typedef __attribute__((ext_vector_type(4))) float float4v;

// ---------------- utility ----------------

__global__ void k_zero(float* __restrict__ p, int n){
  int i = blockIdx.x*256 + threadIdx.x;
  if (i < n) p[i] = 0.f;
}

// mem-prep only: column sums (atomic cm) + row-L2-norm fp16 copy, 4-row ILP, 128 blocks
__global__ __launch_bounds__(256) void k_stage1(
    const float* __restrict__ mem, float* __restrict__ cm, _Float16* __restrict__ mem_h)
{
  __shared__ float smem[4][132];
  const int blk = blockIdx.x, t = threadIdx.x;
  const int wv = t >> 6, lane = t & 63;
  int rbase = blk*16 + wv*4;
  float x0[4], x1[4], ss[4];
  #pragma unroll
  for (int u = 0; u < 4; u++){
    const float* a = mem + (size_t)(rbase+u)*128;
    x0[u] = a[lane]; x1[u] = a[lane+64];
  }
  #pragma unroll
  for (int u = 0; u < 4; u++) ss[u] = x0[u]*x0[u] + x1[u]*x1[u];
  #pragma unroll
  for (int o = 1; o < 64; o <<= 1){
    #pragma unroll
    for (int u = 0; u < 4; u++) ss[u] += __shfl_xor(ss[u], o);
  }
  float c0 = 0.f, c1 = 0.f;
  #pragma unroll
  for (int u = 0; u < 4; u++){
    float invn = 1.f / fmaxf(sqrtf(ss[u]), 1e-12f);
    mem_h[(size_t)(rbase+u)*128 + lane]      = (_Float16)(x0[u]*invn);
    mem_h[(size_t)(rbase+u)*128 + 64 + lane] = (_Float16)(x1[u]*invn);
    c0 += x0[u]; c1 += x1[u];
  }
  smem[wv][lane] = c0; smem[wv][64+lane] = c1;
  __syncthreads();
  if (t < 128) atomicAdd(&cm[t], smem[0][t]+smem[1][t]+smem[2][t]+smem[3][t]);
}

// ---------------- GEMM helpers ----------------
#define QA 264
#define QB 520
#define QB3 776

template<typename TB> struct BReg;
template<> struct BReg<_Float16>{
  half8 v;
  DEVI void load(const _Float16* p){ v = *(const half8*)p; }
  DEVI half8 get() const { return v; }
};
template<> struct BReg<float>{
  float4v a, b;
  DEVI void load(const float* p){ a = *(const float4v*)p; b = *(const float4v*)(p+4); }
  DEVI half8 get() const {
    half8 h;
    #pragma unroll
    for (int j = 0; j < 4; j++){ h[j] = (_Float16)a[j]; h[4+j] = (_Float16)b[j]; }
    return h;
  }
};

// A-loader for the cin matrix: k<1024 -> x fp32 (stride 1024); k>=1024 -> cm/2048.
// Raw loads + scale/cvt deferred to the LDS-write point.
struct ARegX {
  float4v a, b; float sc;
  DEVI void load(const float* __restrict__ x, const float* __restrict__ cm, int row, int k){
    const float* p;
    if (k < 1024){ p = x + (size_t)row*1024 + k; sc = 1.f; }
    else         { p = cm + ((k - 1024) & 127); sc = (1.f/2048.f); }
    a = *(const float4v*)p; b = *(const float4v*)(p+4);
  }
  DEVI half8 get() const {
    half8 h;
    #pragma unroll
    for (int j = 0; j < 4; j++){ h[j] = (_Float16)(a[j]*sc); h[4+j] = (_Float16)(b[j]*sc); }
    return h;
  }
};

// depth-2 prefetch NT GEMM (fp16 A; TB = fp16/fp32 B with deferred cvt)
template<typename TB>
__global__ __launch_bounds__(256) void gemm_t(
    const _Float16* __restrict__ A, const TB* __restrict__ Bm, float* __restrict__ C,
    int M, int N, int K,
    const float* __restrict__ bias1, const float* __restrict__ bias2)
{
  __shared__ _Float16 Ah[2][8*QA];
  __shared__ _Float16 Bh[2][8*QB];
  const int tid = threadIdx.x;
  const int m0 = blockIdx.y*32, n0 = blockIdx.x*64;
  const int T = K >> 6;
  const int arow = tid >> 3, aq = tid & 7;
  const int brow = tid >> 3, bq = tid & 7;
  int nB0 = n0 + brow;      if (nB0 >= N) nB0 = N - 1;
  int nB1 = n0 + brow + 32; if (nB1 >= N) nB1 = N - 1;
  const _Float16* Aptr = A + (size_t)(m0 + arow)*K + aq*8;
  const TB* Bp0 = Bm + (size_t)nB0*K + bq*8;
  const TB* Bp1 = Bm + (size_t)nB1*K + bq*8;
  const int wA  = aq*QA + arow*8;
  const int wB0 = bq*QB + brow*8;
  const int wB1 = bq*QB + (brow+32)*8;
  const int wv_ = tid >> 6, lane = tid & 63;
  const int fq = lane >> 4, fr = lane & 15;
  const int m16 = (wv_ & 1)*16, nb = (wv_ >> 1)*32;

  half8 ra0, ra1;
  BReg<TB> rb00, rb10, rb01, rb11;
  ra0 = *(const half8*)(Aptr);
  rb00.load(Bp0); rb10.load(Bp1);
  if (T > 1){
    ra1 = *(const half8*)(Aptr + 64);
    rb01.load(Bp0 + 64); rb11.load(Bp1 + 64);
  }
  *(half8*)&Ah[0][wA]  = ra0;
  *(half8*)&Bh[0][wB0] = rb00.get();
  *(half8*)&Bh[0][wB1] = rb10.get();
  __syncthreads();

  float4v acc0 = {0.f,0.f,0.f,0.f}, acc1 = {0.f,0.f,0.f,0.f};
  for (int t = 0; t < T; t++){
    const int cur = t & 1, nxt = cur ^ 1;
    if (t+2 < T){
      if (cur == 0){
        ra0 = *(const half8*)(Aptr + (t+2)*64);
        rb00.load(Bp0 + (t+2)*64); rb10.load(Bp1 + (t+2)*64);
      } else {
        ra1 = *(const half8*)(Aptr + (t+2)*64);
        rb01.load(Bp0 + (t+2)*64); rb11.load(Bp1 + (t+2)*64);
      }
    }
    #pragma unroll
    for (int s = 0; s < 2; s++){
      int q = s*4 + fq;
      half8 a  = *(half8*)&Ah[cur][q*QA + (m16+fr)*8];
      half8 b0 = *(half8*)&Bh[cur][q*QB + (nb+fr)*8];
      half8 b1 = *(half8*)&Bh[cur][q*QB + (nb+16+fr)*8];
      acc0 = __builtin_amdgcn_mfma_f32_16x16x32_f16(a, b0, acc0, 0, 0, 0);
      acc1 = __builtin_amdgcn_mfma_f32_16x16x32_f16(a, b1, acc1, 0, 0, 0);
    }
    if (t+1 < T){
      if (nxt == 1){
        *(half8*)&Ah[1][wA]  = ra1;
        *(half8*)&Bh[1][wB0] = rb01.get();
        *(half8*)&Bh[1][wB1] = rb11.get();
      } else {
        *(half8*)&Ah[0][wA]  = ra0;
        *(half8*)&Bh[0][wB0] = rb00.get();
        *(half8*)&Bh[0][wB1] = rb10.get();
      }
    }
    __syncthreads();
  }

  const int colA = n0 + nb + fr, colB = colA + 16;
  #pragma unroll
  for (int i = 0; i < 4; i++){
    int m = m0 + m16 + fq*4 + i;
    if (colA < N){
      float v = acc0[i];
      if (bias1) v += bias1[colA];
      if (bias2) v += bias2[colA];
      C[(size_t)m*N + colA] = v;
    }
    if (colB < N){
      float v = acc1[i];
      if (bias1) v += bias1[colB];
      if (bias2) v += bias2[colB];
      C[(size_t)m*N + colB] = v;
    }
  }
}

// output GEMM: A = concat(h_h [1024], ro_h [512]) selected by k-range (both fp16,
// plain loads — address select only). depth-2 prefetch. M=256, N=1024, K=1536.
__global__ __launch_bounds__(256) void gemm_hro(
    const _Float16* __restrict__ Ah_, const _Float16* __restrict__ Aro,
    const float* __restrict__ Bm, float* __restrict__ C,
    const float* __restrict__ bias1)
{
  __shared__ _Float16 Ah[2][8*QA];
  __shared__ _Float16 Bh[2][8*QB];
  const int tid = threadIdx.x;
  const int m0 = blockIdx.y*32, n0 = blockIdx.x*64;
  const int T = 24;
  const int arow = tid >> 3, aq = tid & 7;
  const int brow = tid >> 3, bq = tid & 7;
  const int arw = m0 + arow;
  const float* Bp0 = Bm + (size_t)(n0 + brow)*1536 + bq*8;
  const float* Bp1 = Bm + (size_t)(n0 + brow + 32)*1536 + bq*8;
  const int wA  = aq*QA + arow*8;
  const int wB0 = bq*QB + brow*8;
  const int wB1 = bq*QB + (brow+32)*8;
  const int wv_ = tid >> 6, lane = tid & 63;
  const int fq = lane >> 4, fr = lane & 15;
  const int m16 = (wv_ & 1)*16, nb = (wv_ >> 1)*32;

  auto ldA = [&](int k) -> half8 {
    const _Float16* p = (k < 1024) ? (Ah_ + (size_t)arw*1024 + k)
                                   : (Aro + (size_t)arw*512 + (k - 1024));
    return *(const half8*)p;
  };

  half8 ra0, ra1;
  BReg<float> rb00, rb10, rb01, rb11;
  ra0 = ldA(aq*8);
  rb00.load(Bp0); rb10.load(Bp1);
  ra1 = ldA(aq*8 + 64);
  rb01.load(Bp0 + 64); rb11.load(Bp1 + 64);
  *(half8*)&Ah[0][wA]  = ra0;
  *(half8*)&Bh[0][wB0] = rb00.get();
  *(half8*)&Bh[0][wB1] = rb10.get();
  __syncthreads();

  float4v acc0 = {0.f,0.f,0.f,0.f}, acc1 = {0.f,0.f,0.f,0.f};
  for (int t = 0; t < T; t++){
    const int cur = t & 1, nxt = cur ^ 1;
    if (t+2 < T){
      if (cur == 0){
        ra0 = ldA(aq*8 + (t+2)*64);
        rb00.load(Bp0 + (t+2)*64); rb10.load(Bp1 + (t+2)*64);
      } else {
        ra1 = ldA(aq*8 + (t+2)*64);
        rb01.load(Bp0 + (t+2)*64); rb11.load(Bp1 + (t+2)*64);
      }
    }
    #pragma unroll
    for (int s = 0; s < 2; s++){
      int q = s*4 + fq;
      half8 a  = *(half8*)&Ah[cur][q*QA + (m16+fr)*8];
      half8 b0 = *(half8*)&Bh[cur][q*QB + (nb+fr)*8];
      half8 b1 = *(half8*)&Bh[cur][q*QB + (nb+16+fr)*8];
      acc0 = __builtin_amdgcn_mfma_f32_16x16x32_f16(a, b0, acc0, 0, 0, 0);
      acc1 = __builtin_amdgcn_mfma_f32_16x16x32_f16(a, b1, acc1, 0, 0, 0);
    }
    if (t+1 < T){
      if (nxt == 1){
        *(half8*)&Ah[1][wA]  = ra1;
        *(half8*)&Bh[1][wB0] = rb01.get();
        *(half8*)&Bh[1][wB1] = rb11.get();
      } else {
        *(half8*)&Ah[0][wA]  = ra0;
        *(half8*)&Bh[0][wB0] = rb00.get();
        *(half8*)&Bh[0][wB1] = rb10.get();
      }
    }
    __syncthreads();
  }

  const int colA = n0 + nb + fr, colB = colA + 16;
  #pragma unroll
  for (int i = 0; i < 4; i++){
    int m = m0 + m16 + fq*4 + i;
    C[(size_t)m*1024 + colA] = acc0[i] + bias1[colA];
    C[(size_t)m*1024 + colB] = acc1[i] + bias1[colB];
  }
}

// ww-scores GEMM: C = exp(wv_h @ mem_h^T) + per-row sums into rsum (pre-zeroed)
__global__ __launch_bounds__(256) void k_gemm_wwExp(
    const _Float16* __restrict__ A, const _Float16* __restrict__ Bm,
    float* __restrict__ C, float* __restrict__ rsum)
{
  __shared__ _Float16 Ah[2][8*QA];
  __shared__ _Float16 Bh[2][8*QB];
  const int tid = threadIdx.x;
  const int m0 = blockIdx.y*32, n0 = blockIdx.x*64;
  const int arow = tid >> 3, aq = tid & 7;
  const int brow = tid >> 3, bq = tid & 7;
  const _Float16* Aptr = A + (size_t)(m0 + arow)*128 + aq*8;
  const _Float16* Bp0 = Bm + (size_t)(n0 + brow)*128 + bq*8;
  const _Float16* Bp1 = Bm + (size_t)(n0 + brow + 32)*128 + bq*8;
  const int wA  = aq*QA + arow*8;
  const int wB0 = bq*QB + brow*8;
  const int wB1 = bq*QB + (brow+32)*8;
  const int wv_ = tid >> 6, lane = tid & 63;
  const int fq = lane >> 4, fr = lane & 15;
  const int m16 = (wv_ & 1)*16, nb = (wv_ >> 1)*32;

  half8 ra  = *(const half8*)(Aptr);
  half8 rb0 = *(const half8*)(Bp0);
  half8 rb1 = *(const half8*)(Bp1);
  *(half8*)&Ah[0][wA]  = ra;
  *(half8*)&Bh[0][wB0] = rb0;
  *(half8*)&Bh[0][wB1] = rb1;
  __syncthreads();

  float4v acc0 = {0.f,0.f,0.f,0.f}, acc1 = {0.f,0.f,0.f,0.f};
  for (int t = 0; t < 2; t++){
    const int cur = t & 1, nxt = cur ^ 1;
    if (t == 0){
      ra  = *(const half8*)(Aptr + 64);
      rb0 = *(const half8*)(Bp0 + 64);
      rb1 = *(const half8*)(Bp1 + 64);
    }
    #pragma unroll
    for (int s = 0; s < 2; s++){
      int q = s*4 + fq;
      half8 a  = *(half8*)&Ah[cur][q*QA + (m16+fr)*8];
      half8 b0 = *(half8*)&Bh[cur][q*QB + (nb+fr)*8];
      half8 b1 = *(half8*)&Bh[cur][q*QB + (nb+16+fr)*8];
      acc0 = __builtin_amdgcn_mfma_f32_16x16x32_f16(a, b0, acc0, 0, 0, 0);
      acc1 = __builtin_amdgcn_mfma_f32_16x16x32_f16(a, b1, acc1, 0, 0, 0);
    }
    if (t == 0){
      *(half8*)&Ah[nxt][wA]  = ra;
      *(half8*)&Bh[nxt][wB0] = rb0;
      *(half8*)&Bh[nxt][wB1] = rb1;
    }
    __syncthreads();
  }

  const int colA = n0 + nb + fr, colB = colA + 16;
  #pragma unroll
  for (int i = 0; i < 4; i++){
    int m = m0 + m16 + fq*4 + i;
    float e0 = expf(acc0[i]);
    float e1 = expf(acc1[i]);
    C[(size_t)m*2048 + colA] = e0;
    C[(size_t)m*2048 + colB] = e1;
    float rs = e0 + e1;
    #pragma unroll
    for (int o = 1; o < 16; o <<= 1) rs += __shfl_xor(rs, o);
    if (fr == 0) atomicAdd(&rsum[m], rs);
  }
}

// -------- merged launch: LSTM gate-GEMM [0,256) | link sums [256,512) | alloc [512,1024)
__global__ __launch_bounds__(256) void k_big2(
    const float* __restrict__ x, const float* __restrict__ cm,
    const float* __restrict__ W,
    const float* __restrict__ b_ih, const float* __restrict__ b_hh,
    _Float16* __restrict__ h,
    const float* __restrict__ usage, float* __restrict__ alloc,
    const float* __restrict__ link, float* __restrict__ rsl, float* __restrict__ cslp)
{
  extern __shared__ char smraw[];
  const int blk = blockIdx.x, tid = threadIdx.x;
  const int wv = tid >> 6, lane = tid & 63;

  if (blk < 256){
    _Float16* AhP = (_Float16*)smraw;                                  // [2][8*QA]
    _Float16* BhP = (_Float16*)(smraw + 2*8*QA*sizeof(_Float16));      // [2][8*QB3]
    const int SA = 8*QA, SB = 8*QB3;
    const int m0 = (blk >> 5)*32, c0 = (blk & 31)*32;
    const int T = 24;                              // K = 1536
    const int arow = tid >> 3, aq = tid & 7;
    const int brow = tid >> 3, bq = tid & 7;
    const int arw = m0 + arow;
    const float* Bpi = W + (size_t)(       c0 + brow)*1536 + bq*8;
    const float* Bpg = W + (size_t)(2048 + c0 + brow)*1536 + bq*8;
    const float* Bpo = W + (size_t)(3072 + c0 + brow)*1536 + bq*8;
    const int wA  = aq*QA + arow*8;
    const int wBi = bq*QB3 + brow*8;
    const int wBg = bq*QB3 + (32+brow)*8;
    const int wBo = bq*QB3 + (64+brow)*8;
    const int fq = lane >> 4, fr = lane & 15;
    const int m16 = (wv & 1)*16, c16 = (wv >> 1)*16;

    ARegX ax0, ax1;
    BReg<float> ri0, rg0, ro0, ri1, rg1, ro1;
    ax0.load(x, cm, arw, aq*8);
    ri0.load(Bpi); rg0.load(Bpg); ro0.load(Bpo);
    ax1.load(x, cm, arw, aq*8 + 64);
    ri1.load(Bpi + 64); rg1.load(Bpg + 64); ro1.load(Bpo + 64);
    *(half8*)&AhP[wA]  = ax0.get();
    *(half8*)&BhP[wBi] = ri0.get();
    *(half8*)&BhP[wBg] = rg0.get();
    *(half8*)&BhP[wBo] = ro0.get();
    __syncthreads();

    float4v acci = {0.f,0.f,0.f,0.f}, accg = {0.f,0.f,0.f,0.f}, acco = {0.f,0.f,0.f,0.f};
    for (int t = 0; t < T; t++){
      const int cur = t & 1, nxt = cur ^ 1;
      if (t+2 < T){
        if (cur == 0){
          ax0.load(x, cm, arw, aq*8 + (t+2)*64);
          ri0.load(Bpi + (t+2)*64); rg0.load(Bpg + (t+2)*64); ro0.load(Bpo + (t+2)*64);
        } else {
          ax1.load(x, cm, arw, aq*8 + (t+2)*64);
          ri1.load(Bpi + (t+2)*64); rg1.load(Bpg + (t+2)*64); ro1.load(Bpo + (t+2)*64);
        }
      }
      #pragma unroll
      for (int s = 0; s < 2; s++){
        int q = s*4 + fq;
        half8 a  = *(half8*)&AhP[cur*SA + q*QA + (m16+fr)*8];
        half8 bi = *(half8*)&BhP[cur*SB + q*QB3 + (c16+fr)*8];
        half8 bg = *(half8*)&BhP[cur*SB + q*QB3 + (32+c16+fr)*8];
        half8 bo = *(half8*)&BhP[cur*SB + q*QB3 + (64+c16+fr)*8];
        acci = __builtin_amdgcn_mfma_f32_16x16x32_f16(a, bi, acci, 0, 0, 0);
        accg = __builtin_amdgcn_mfma_f32_16x16x32_f16(a, bg, accg, 0, 0, 0);
        acco = __builtin_amdgcn_mfma_f32_16x16x32_f16(a, bo, acco, 0, 0, 0);
      }
      if (t+1 < T){
        if (nxt == 1){
          *(half8*)&AhP[SA + wA]  = ax1.get();
          *(half8*)&BhP[SB + wBi] = ri1.get();
          *(half8*)&BhP[SB + wBg] = rg1.get();
          *(half8*)&BhP[SB + wBo] = ro1.get();
        } else {
          *(half8*)&AhP[wA]  = ax0.get();
          *(half8*)&BhP[wBi] = ri0.get();
          *(half8*)&BhP[wBg] = rg0.get();
          *(half8*)&BhP[wBo] = ro0.get();
        }
      }
      __syncthreads();
    }

    const int col = c0 + c16 + fr;
    const float bi1 = b_ih[col]        + b_hh[col];
    const float bg1 = b_ih[2048 + col] + b_hh[2048 + col];
    const float bo1 = b_ih[3072 + col] + b_hh[3072 + col];
    #pragma unroll
    for (int i = 0; i < 4; i++){
      int m = m0 + m16 + fq*4 + i;
      float gi = acci[i] + bi1;
      float gg = accg[i] + bg1;
      float go = acco[i] + bo1;
      float c = sigm(gi) * tanhf(gg);
      h[(size_t)m*1024 + col] = (_Float16)(sigm(go) * tanhf(c));
    }
  } else if (blk < 512){
    float (*smem)[132] = (float(*)[132])smraw;
    int pb = blk - 256;
    int r0 = pb*8;
    int c0 = tid*8;
    float4v v0[8], v1[8];
    #pragma unroll
    for (int u = 0; u < 8; u++){
      const float* lp = link + (size_t)(r0+u)*2048 + c0;
      v0[u] = *(const float4v*)lp;
      v1[u] = *(const float4v*)(lp+4);
    }
    float colacc[8];
    #pragma unroll
    for (int j = 0; j < 8; j++) colacc[j] = 0.f;
    float rowpart[8];
    #pragma unroll
    for (int u = 0; u < 8; u++){
      float s = 0.f;
      #pragma unroll
      for (int j = 0; j < 4; j++){
        colacc[j]   += v0[u][j]; colacc[4+j] += v1[u][j];
        s += v0[u][j] + v1[u][j];
      }
      rowpart[u] = s;
    }
    #pragma unroll
    for (int o = 1; o < 64; o <<= 1){
      #pragma unroll
      for (int u = 0; u < 8; u++) rowpart[u] += __shfl_xor(rowpart[u], o);
    }
    if (lane == 0){
      #pragma unroll
      for (int u = 0; u < 8; u++) smem[wv][u] = rowpart[u];
    }
    __syncthreads();
    if (tid < 8) rsl[r0+tid] = smem[0][tid]+smem[1][tid]+smem[2][tid]+smem[3][tid];
    float4v w0, w1;
    #pragma unroll
    for (int j = 0; j < 4; j++){ w0[j] = colacc[j]; w1[j] = colacc[4+j]; }
    *(float4v*)&cslp[(size_t)pb*2048 + c0]     = w0;
    *(float4v*)&cslp[(size_t)pb*2048 + c0 + 4] = w1;
  } else {
    int n = (blk - 512)*4 + wv;
    float un = usage[n];
    float prod = 1.f;
    #pragma unroll
    for (int i = 0; i < 32; i++){
      int m = lane + i*64;
      float um = usage[m];
      bool before = (um < un) || (um == un && m < n);
      prod *= before ? (1.f - um) : 1.f;
    }
    #pragma unroll
    for (int o = 32; o > 0; o >>= 1) prod *= __shfl_xor(prod, o);
    if (lane == 0) alloc[n] = un * prod;
  }
}

DEVI float blockReduce128(float v, float* lds2){
  #pragma unroll
  for (int o = 32; o > 0; o >>= 1) v += __shfl_xor(v, o);
  int w = threadIdx.x >> 6;
  __syncthreads();
  if ((threadIdx.x & 63) == 0) lds2[w] = v;
  __syncthreads();
  return lds2[0] + lds2[1];
}

// parse itf; wv_h has invwv folded, rks_h has invk*str folded
__global__ __launch_bounds__(128) void k_parse(const float* __restrict__ itf,
    _Float16* __restrict__ wv_h, float* __restrict__ ev, float* __restrict__ av,
    float* __restrict__ wg_, float* __restrict__ ag_,
    float* __restrict__ rm0, float* __restrict__ rm1, float* __restrict__ rm2,
    _Float16* __restrict__ rks_h)
{
  __shared__ float red[2];
  int b = blockIdx.x, t = threadIdx.x;
  const float* it = itf + (size_t)b*787;
  float wg = sigm(it[256]);
  float ag = sigm(it[257]);
  if (t == 0){ wg_[b] = wg; ag_[b] = ag; }
  float w = it[t];
  av[b*128 + t] = w * wg;
  ev[b*128 + t] = sigm(it[128 + t]) * wg;
  float ss = blockReduce128(w*w, red);
  float invwv = 1.f / fmaxf(sqrtf(ss), 1e-12f);
  wv_h[b*128 + t] = (_Float16)(w * invwv);
  if (t < 4){
    int rr = t;
    float m0v = it[259 + rr*3 + 0], m1v = it[259 + rr*3 + 1], m2v = it[259 + rr*3 + 2];
    float mx = fmaxf(m0v, fmaxf(m1v, m2v));
    float e0 = expf(m0v - mx), e1 = expf(m1v - mx), e2 = expf(m2v - mx);
    float inv = 1.f / (e0 + e1 + e2);
    rm0[b*4 + rr] = e0*inv; rm1[b*4 + rr] = e1*inv; rm2[b*4 + rr] = e2*inv;
  }
  #pragma unroll
  for (int rr = 0; rr < 4; rr++){
    float kv = it[275 + rr*128 + t];
    float ks = blockReduce128(kv*kv, red);
    float sx = it[271 + rr];
    float str = fmaxf(sx, 0.f) + log1pf(expf(-fabsf(sx)));
    float invk = 1.f / fmaxf(sqrtf(ks), 1e-12f);
    rks_h[((size_t)b*4 + rr)*128 + t] = (_Float16)(kv * invk * str);
  }
}

// fused memory update + softmax-weighting + bw/fw + csl reduction.
//   ww holds exp(scores); w = c1[b]*e + c2[b]*alloc[n] applied at staging.
//   Inner compute uses float4 LDS reads (ds_read_b128): 3 reads/k instead of 12
//   scalar reads; global loads for the next k0 are issued under the compute.
__global__ __launch_bounds__(256) void k_memupdate_fused(const float* __restrict__ ww,
    const float* __restrict__ ev, const float* __restrict__ av,
    const float* __restrict__ mem,
    const float* __restrict__ wg, const float* __restrict__ ag,
    const float* __restrict__ alloc, const float* __restrict__ rsum,
    const float* __restrict__ rsl, const float* __restrict__ cslp,
    _Float16* __restrict__ memn_h, _Float16* __restrict__ memnT_h,
    float* __restrict__ bwm, float* __restrict__ fwm)
{
  __shared__ float Ws[16][36];     // padded to 36 for 16B-aligned float4 rows
  __shared__ float Es[16][132], Vs[16][132];
  __shared__ float lb[128], lf[128];
  __shared__ _Float16 Traw[32][132];
  __shared__ float tbs[256], c1s[256], c2s[256];
  __shared__ float allocL[32];
  __shared__ float sq[8][32], sd[8][32];
  __shared__ float cpart[8][32];
  __shared__ float bwL[32], fwL[32];
  __shared__ float sred[4];
  const int n0 = blockIdx.x*32;
  const int tid = threadIdx.x, tx = tid & 31, ty = tid >> 5;

  {
    float sa = 0.f;
    #pragma unroll
    for (int i = 0; i < 8; i++) sa += alloc[tid + i*256];
    #pragma unroll
    for (int o = 32; o > 0; o >>= 1) sa += __shfl_xor(sa, o);
    if ((tid & 63) == 0) sred[tid >> 6] = sa;
    if (tid < 128){ lb[tid] = 0.f; lf[tid] = 0.f; }
    if (tid < 32) allocL[tid] = alloc[n0 + tid];
    __syncthreads();
    sa = (sred[0]+sred[1]) + (sred[2]+sred[3]);
    float w = wg[tid], a = ag[tid];
    tbs[tid] = w*(0.5f + 0.5f*a*sa);
    c1s[tid] = 0.5f*w / rsum[tid];
    c2s[tid] = 0.5f*w*a;
  }
  {
    int col = n0 + tx;
    float s = 0.f;
    for (int p = ty*32; p < ty*32 + 32; p += 4){
      s += cslp[(size_t)(p+0)*2048 + col] + cslp[(size_t)(p+1)*2048 + col]
         + cslp[(size_t)(p+2)*2048 + col] + cslp[(size_t)(p+3)*2048 + col];
    }
    cpart[ty][tx] = s;
  }

  const int wk = tid >> 4, wn = (tid & 15)*2;
  const int ek = tid >> 4, ec = (tid & 15)*8;
  float ae[4][4] = {}, aa[4][4] = {};
  float qp = 0.f, ddp = 0.f;

  // preload k0 = 0
  float2 vw   = *(const float2*)(ww + (size_t)wk*2048 + n0 + wn);
  float4 ve0  = *(const float4*)(ev + (size_t)ek*128 + ec);
  float4 ve1  = *(const float4*)(ev + (size_t)ek*128 + ec + 4);
  float4 va0  = *(const float4*)(av + (size_t)ek*128 + ec);
  float4 va1  = *(const float4*)(av + (size_t)ek*128 + ec + 4);

  for (int k0 = 0; k0 < 256; k0 += 16){
    __syncthreads();
    {
      float cb1 = c1s[k0+wk], cb2 = c2s[k0+wk];
      Ws[wk][wn]   = cb1*vw.x + cb2*allocL[wn];
      Ws[wk][wn+1] = cb1*vw.y + cb2*allocL[wn+1];
    }
    *(float4*)&Es[ek][ec] = ve0; *(float4*)&Es[ek][ec+4] = ve1;
    *(float4*)&Vs[ek][ec] = va0; *(float4*)&Vs[ek][ec+4] = va1;
    __syncthreads();
    // issue next-tile global loads under the compute
    if (k0 + 16 < 256){
      vw  = *(const float2*)(ww + (size_t)(k0+16+wk)*2048 + n0 + wn);
      ve0 = *(const float4*)(ev + (size_t)(k0+16+ek)*128 + ec);
      ve1 = *(const float4*)(ev + (size_t)(k0+16+ek)*128 + ec + 4);
      va0 = *(const float4*)(av + (size_t)(k0+16+ek)*128 + ec);
      va1 = *(const float4*)(av + (size_t)(k0+16+ek)*128 + ec + 4);
    }
    #pragma unroll
    for (int k = 0; k < 16; k++){
      float4v a4 = *(const float4v*)&Ws[k][ty*4];
      float4v e4 = *(const float4v*)&Es[k][tx*4];
      float4v v4 = *(const float4v*)&Vs[k][tx*4];
      #pragma unroll
      for (int i = 0; i < 4; i++)
        #pragma unroll
        for (int j = 0; j < 4; j++){
          ae[i][j] = fmaf(a4[i], e4[j], ae[i][j]);
          aa[i][j] = fmaf(a4[i], v4[j], aa[i][j]);
        }
    }
    {
      float w0 = Ws[ty*2+0][tx], w1 = Ws[ty*2+1][tx];
      qp  = fmaf(tbs[k0+ty*2+0], w0, qp);  ddp = fmaf(w0, w0, ddp);
      qp  = fmaf(tbs[k0+ty*2+1], w1, qp);  ddp = fmaf(w1, w1, ddp);
    }
  }
  sq[ty][tx] = qp; sd[ty][tx] = ddp;
  __syncthreads();
  if (tid < 32){
    float q = 0.f, dd = 0.f, cs = 0.f;
    #pragma unroll
    for (int z = 0; z < 8; z++){ q += sq[z][tid]; dd += sd[z][tid]; cs += cpart[z][tid]; }
    float lus = (q - dd) * (1.f/256.f);
    bwL[tid] = (0.9f*cs + 0.1f*lus) * (1.f/2048.f);
    fwL[tid] = (0.9f*rsl[n0+tid] + 0.1f*lus) * (1.f/2048.f);
  }
  __syncthreads();

  float ab[4] = {0,0,0,0}, af[4] = {0,0,0,0};
  #pragma unroll
  for (int i = 0; i < 4; i++){
    int n = n0 + ty*4 + i;
    float bwn = bwL[ty*4+i], fwn = fwL[ty*4+i];
    float v[4]; float ss = 0.f;
    #pragma unroll
    for (int j = 0; j < 4; j++){
      int d = tx*4 + j;
      float em = ae[i][j]*(1.f/256.f), am = aa[i][j]*(1.f/256.f);
      float mv = mem[(size_t)n*128 + d]*(1.f - em) + am;
      v[j] = mv; ss += mv*mv;
      ab[j] = fmaf(bwn, mv, ab[j]);
      af[j] = fmaf(fwn, mv, af[j]);
    }
    #pragma unroll
    for (int o = 1; o < 32; o <<= 1) ss += __shfl_xor(ss, o);
    float invn = 1.f / fmaxf(sqrtf(ss), 1e-12f);
    half4 hn, hr;
    #pragma unroll
    for (int j = 0; j < 4; j++){ hn[j] = (_Float16)(v[j]*invn); hr[j] = (_Float16)v[j]; }
    *(half4*)(memn_h + (size_t)n*128 + tx*4) = hn;
    *(half4*)&Traw[ty*4+i][tx*4] = hr;
  }
  __syncthreads();
  {
    int d = tid >> 1, seg = (tid & 1)*16;
    half8 o0, o1;
    #pragma unroll
    for (int j = 0; j < 8; j++){ o0[j] = Traw[seg+j][d]; o1[j] = Traw[seg+8+j][d]; }
    *(half8*)(memnT_h + (size_t)d*2048 + n0 + seg)     = o0;
    *(half8*)(memnT_h + (size_t)d*2048 + n0 + seg + 8) = o1;
  }
  #pragma unroll
  for (int j = 0; j < 4; j++){
    atomicAdd(&lb[tx*4+j], ab[j]);
    atomicAdd(&lf[tx*4+j], af[j]);
  }
  __syncthreads();
  if (tid < 128){
    atomicAdd(&bwm[tid], lb[tid]);
    atomicAdd(&fwm[tid], lf[tid]);
  }
}

// flash-style fused read addressing — 8 key-chunks of 256 keys (2 s-steps/block)
__global__ __launch_bounds__(256) void k_flash(
    const _Float16* __restrict__ Q, const _Float16* __restrict__ Kh,
    const _Float16* __restrict__ Vt,
    float* __restrict__ pacc, float* __restrict__ pm, float* __restrict__ pl)
{
  __shared__ _Float16 Pl[4][16][32];
  __shared__ float cmb[4][2080];
  __shared__ float scl[4][16];
  const int tid = threadIdx.x;
  const int qt = blockIdx.x >> 3, kc = blockIdx.x & 7;
  const int wv = tid >> 6, lane = tid & 63;
  const int fq = lane >> 4, fr = lane & 15;
  const int kw0 = kc*256 + wv*64;

  half8 aq[4];
  #pragma unroll
  for (int c = 0; c < 4; c++)
    aq[c] = *(const half8*)(Q + (size_t)(qt*16 + fr)*128 + c*32 + fq*8);

  float m[4] = {-3.0e38f,-3.0e38f,-3.0e38f,-3.0e38f};
  float l[4] = {0.f,0.f,0.f,0.f};
  float4v acc[8] = {};
  for (int s = 0; s < 2; s++){
    const int kb = kw0 + s*32;
    float4v S0 = {0,0,0,0}, S1 = {0,0,0,0};
    #pragma unroll
    for (int c = 0; c < 4; c++){
      half8 b0 = *(const half8*)(Kh + (size_t)(kb + fr)*128      + c*32 + fq*8);
      half8 b1 = *(const half8*)(Kh + (size_t)(kb + 16 + fr)*128 + c*32 + fq*8);
      S0 = __builtin_amdgcn_mfma_f32_16x16x32_f16(aq[c], b0, S0, 0, 0, 0);
      S1 = __builtin_amdgcn_mfma_f32_16x16x32_f16(aq[c], b1, S1, 0, 0, 0);
    }
    float mt[4], ps[4];
    #pragma unroll
    for (int i = 0; i < 4; i++) mt[i] = fmaxf(S0[i], S1[i]);
    #pragma unroll
    for (int o = 1; o < 16; o <<= 1){
      #pragma unroll
      for (int i = 0; i < 4; i++) mt[i] = fmaxf(mt[i], __shfl_xor(mt[i], o));
    }
    #pragma unroll
    for (int i = 0; i < 4; i++){
      float mn = fmaxf(m[i], mt[i]);
      float al = expf(m[i] - mn);
      float p0 = expf(S0[i] - mn), p1 = expf(S1[i] - mn);
      S0[i] = p0; S1[i] = p1;
      ps[i] = p0 + p1;
      l[i] *= al;
      m[i] = mn;
      #pragma unroll
      for (int c = 0; c < 8; c++) acc[c][i] *= al;
    }
    #pragma unroll
    for (int o = 1; o < 16; o <<= 1){
      #pragma unroll
      for (int i = 0; i < 4; i++) ps[i] += __shfl_xor(ps[i], o);
    }
    #pragma unroll
    for (int i = 0; i < 4; i++) l[i] += ps[i];
    #pragma unroll
    for (int i = 0; i < 4; i++){
      Pl[wv][fq*4+i][fr]      = (_Float16)S0[i];
      Pl[wv][fq*4+i][16 + fr] = (_Float16)S1[i];
    }
    half8 pf = *(half8*)&Pl[wv][fr][fq*8];
    #pragma unroll
    for (int c = 0; c < 8; c++){
      half8 bv = *(const half8*)(Vt + (size_t)(c*16 + fr)*2048 + kb + fq*8);
      acc[c] = __builtin_amdgcn_mfma_f32_16x16x32_f16(pf, bv, acc[c], 0, 0, 0);
    }
  }
  if (fr == 0){
    #pragma unroll
    for (int i = 0; i < 4; i++){
      cmb[wv][fq*4+i]      = m[i];
      cmb[wv][16 + fq*4+i] = l[i];
    }
  }
  #pragma unroll
  for (int c = 0; c < 8; c++)
    #pragma unroll
    for (int i = 0; i < 4; i++)
      cmb[wv][32 + (fq*4+i)*128 + c*16 + fr] = acc[c][i];
  __syncthreads();
  if (tid < 16){
    float mm = fmaxf(fmaxf(cmb[0][tid], cmb[1][tid]), fmaxf(cmb[2][tid], cmb[3][tid]));
    float ll = 0.f;
    #pragma unroll
    for (int w = 0; w < 4; w++){
      float e = expf(cmb[w][tid] - mm);
      scl[w][tid] = e;
      ll += e * cmb[w][16 + tid];
    }
    pm[blockIdx.x*16 + tid] = mm;
    pl[blockIdx.x*16 + tid] = ll;
  }
  __syncthreads();
  for (int e = tid; e < 2048; e += 256){
    int q = e >> 7;
    float a = scl[0][q]*cmb[0][32+e] + scl[1][q]*cmb[1][32+e]
            + scl[2][q]*cmb[2][32+e] + scl[3][q]*cmb[3][32+e];
    pacc[(size_t)blockIdx.x*2048 + e] = a;
  }
}

// flash partial combine (8 chunks) + read-mode mix -> ro fp16
__global__ void k_ro(const float* __restrict__ pacc, const float* __restrict__ pm,
                     const float* __restrict__ pl,
                     const float* __restrict__ rm0, const float* __restrict__ rm1,
                     const float* __restrict__ rm2, const float* __restrict__ bwm,
                     const float* __restrict__ fwm, _Float16* __restrict__ ro){
  int idx = blockIdx.x*256 + threadIdx.x;   // 131072
  int row = idx >> 7, d = idx & 127;
  int qt = row >> 4, q = row & 15;
  float mm = -3.0e38f;
  #pragma unroll
  for (int kc = 0; kc < 8; kc++) mm = fmaxf(mm, pm[(qt*8+kc)*16 + q]);
  float num = 0.f, den = 0.f;
  #pragma unroll
  for (int kc = 0; kc < 8; kc++){
    float e = expf(pm[(qt*8+kc)*16 + q] - mm);
    den += e * pl[(qt*8+kc)*16 + q];
    num += e * pacc[(size_t)(qt*8+kc)*2048 + q*128 + d];
  }
  float pv = num / den;
  ro[idx] = (_Float16)(rm0[row]*pv + rm1[row]*bwm[d] + rm2[row]*fwm[d]);
}

// ---------------- launcher ----------------

extern "C" void kernel_launch(void* const* d_in, const int* in_sizes, int n_in,
                              void* d_out, int out_size, void* d_ws, size_t ws_size,
                              hipStream_t stream)
{
  const float* x     = (const float*)d_in[0];
  const float* mem   = (const float*)d_in[1];
  const float* usage = (const float*)d_in[2];
  const float* link  = (const float*)d_in[3];
  const float* W_ih  = (const float*)d_in[4];
  // d_in[5] = W_hh: unused (h0 = 0)
  const float* b_ih  = (const float*)d_in[6];
  const float* b_hh  = (const float*)d_in[7];
  const float* W_if  = (const float*)d_in[8];
  const float* b_if  = (const float*)d_in[9];
  const float* W_out = (const float*)d_in[10];
  const float* b_out = (const float*)d_in[11];
  float* out = (float*)d_out;
  float* ws  = (float*)d_ws;

  // fp32 scratch
  float* cm     = ws + 0;         // 128   (zero region: [0,2688) covers cm,bwm,fwm,rsum)
  float* bwm    = ws + 2176;      // 128
  float* fwm    = ws + 2304;      // 128
  float* rsum   = ws + 2432;      // 256 (exp row sums)
  float* wg     = ws + 6784;      // 256
  float* ag     = ws + 7040;      // 256
  float* rm0    = ws + 7296;      // 1024
  float* rm1    = ws + 8320;      // 1024
  float* rm2    = ws + 9344;      // 1024
  float* alloc  = ws + 10368;     // 2048
  float* rsl    = ws + 12416;     // 2048
  float* ev     = ws + 14464;     // 32768 (B x 128)
  float* av     = ws + 47232;     // 32768
  float* itf    = ws + 1128576;   // 201472 (B x 787)
  float* ww     = ws + 1330048;   // 524288 (B x 2048, exp scores)
  float* pacc   = ws + 1854336;   // 1048576 (512 blocks x 2048)
  float* pm     = ws + 2902912;   // 8192
  float* pl     = ws + 2911104;   // 8192
  // fp16 scratch
  _Float16* wv_h    = (_Float16*)(ws + 2919296);  //  32,768 h
  _Float16* mem_h   = (_Float16*)(ws + 2935680);  // 262,144 h (row-normalized)
  _Float16* memn_h  = (_Float16*)(ws + 3066752);  // 262,144 h (row-normalized)
  _Float16* memnT_h = (_Float16*)(ws + 3197824);  // 262,144 h (transposed raw)
  _Float16* rks_h   = (_Float16*)(ws + 3328896);  // 131,072 h
  _Float16* ro_h    = (_Float16*)(ws + 3394432);  // 131,072 h (read-out)
  _Float16* h_h     = (_Float16*)(ws + 3459968);  // 262,144 h
  float* cslp       = ws + 3591040;               // 524,288 (256 x 2048 col partials)
  // total ~4.1M floats = 16.5 MB

  const int SH_BIG2 = (2*8*QA + 2*8*QB3) * (int)sizeof(_Float16);   // 33280 B

  // stage 0: zero atomic accumulators (cm, bwm, fwm, rsum)
  k_zero<<<11, 256, 0, stream>>>(ws, 2688);

  // stage 1: mem colsum + rownorm (cm, mem_h) — prerequisite of the big launch
  k_stage1<<<128, 256, 0, stream>>>(mem, cm, mem_h);

  // stage 2 (merged): LSTM gate GEMM+activation | link row/col sums | alloc
  k_big2<<<1024, 256, SH_BIG2, stream>>>(x, cm, W_ih, b_ih, b_hh, h_h,
                                         usage, alloc, link, rsl, cslp);

  // stage 3: interface (B = W_if fp32, deferred-cvt, depth-2 prefetch)
  gemm_t<float><<<dim3(13,8), 256, 0, stream>>>(h_h, W_if, itf, 256, 787, 1024, b_if, nullptr);
  k_parse<<<256, 128, 0, stream>>>(itf, wv_h, ev, av, wg, ag, rm0, rm1, rm2, rks_h);

  // stage 4: write scores -> exp + row sums
  k_gemm_wwExp<<<dim3(32,8), 256, 0, stream>>>(wv_h, mem_h, ww, rsum);

  // stage 5+6: memory update (float4 LDS reads + pipelined k0 loads)
  k_memupdate_fused<<<64, 256, 0, stream>>>(ww, ev, av, mem, wg, ag, alloc, rsum,
                                            rsl, cslp, memn_h, memnT_h, bwm, fwm);

  // stage 7: flash-fused read addressing (8 key-chunks)
  k_flash<<<512, 256, 0, stream>>>(rks_h, memn_h, memnT_h, pacc, pm, pl);

  // stage 8: read-out combine (8 chunks) + output projection (depth-2 prefetch)
  k_ro<<<512, 256, 0, stream>>>(pacc, pm, pl, rm0, rm1, rm2, bwm, fwm, ro_h);
  gemm_hro<<<dim3(16,8), 256, 0, stream>>>(h_h, ro_h, W_out, out, b_out);

  (void)in_sizes; (void)n_in; (void)out_size; (void)ws_size;
}